// Round 1
// baseline (581.627 us; speedup 1.0000x reference)
//
#include <hip/hip_runtime.h>

#define FDIM 128
#define LN_EPS 1e-5f

// ---------------- CSR build ----------------
__global__ void k_zero(int* __restrict__ cnt, int n) {
    int i = blockIdx.x * 256 + threadIdx.x;
    if (i < n) cnt[i] = 0;
}

// count in-degree (dst side), remember each edge's slot within its dst bucket
__global__ void k_count(const int* __restrict__ dst, int* __restrict__ cnt,
                        int* __restrict__ pos, int E) {
    int e = blockIdx.x * 256 + threadIdx.x;
    if (e < E) pos[e] = atomicAdd(&cnt[dst[e]], 1);
}

__global__ __launch_bounds__(1024) void k_scan_block(const int* __restrict__ cnt,
                                                     int* __restrict__ rowptr,
                                                     int* __restrict__ partial, int N) {
    __shared__ int s[1024];
    int t = threadIdx.x;
    int i = blockIdx.x * 1024 + t;
    int v = (i < N) ? cnt[i] : 0;
    s[t] = v;
    __syncthreads();
    for (int off = 1; off < 1024; off <<= 1) {
        int u = (t >= off) ? s[t - off] : 0;
        __syncthreads();
        s[t] += u;
        __syncthreads();
    }
    if (i < N) rowptr[i] = s[t] - v;             // block-local exclusive
    if (t == 1023) partial[blockIdx.x] = s[1023]; // block total
}

__global__ __launch_bounds__(1024) void k_scan_partial(int* __restrict__ partial, int NB) {
    __shared__ int s[1024];
    int t = threadIdx.x;
    int v = (t < NB) ? partial[t] : 0;
    s[t] = v;
    __syncthreads();
    for (int off = 1; off < 1024; off <<= 1) {
        int u = (t >= off) ? s[t - off] : 0;
        __syncthreads();
        s[t] += u;
        __syncthreads();
    }
    if (t < NB) partial[t] = s[t] - v;           // exclusive block offsets
}

__global__ void k_finalize(int* __restrict__ rowptr, const int* __restrict__ partial,
                           const int* __restrict__ cnt, float* __restrict__ dinv,
                           int N, int E) {
    int i = blockIdx.x * 256 + threadIdx.x;
    if (i < N) {
        rowptr[i] += partial[i >> 10];
        dinv[i] = rsqrtf((float)cnt[i] + 1.0f);  // deg = indegree + self-loop
    }
    if (i == 0) rowptr[N] = E;
}

__global__ void k_fill(const int* __restrict__ src, const int* __restrict__ dst,
                       const int* __restrict__ rowptr, const int* __restrict__ pos,
                       int* __restrict__ col, int E) {
    int e = blockIdx.x * 256 + threadIdx.x;
    if (e < E) col[rowptr[dst[e]] + pos[e]] = src[e];
}

// ---------------- fp32 GEMM: H[N,128] = X[N,128] @ W[128,128] ----------------
// 256 threads, 128 rows/block, k tiled by 64 (2 stages, 64 KiB LDS).
// Thread (cg=t&15, rg=t>>4) computes rows 8rg..8rg+7 x cols 8cg..8cg+7.
// sX holds x^T (k-major) with XOR group swizzle -> conflict-free b128 A reads.
__global__ __launch_bounds__(256) void k_gemm(const float* __restrict__ X,
                                              const float* __restrict__ W,
                                              float* __restrict__ H, int N) {
    __shared__ float sW[64 * 128];
    __shared__ float sX[64 * 128];
    float4* sW4 = (float4*)sW;
    float4* sX4 = (float4*)sX;
    const float4* W4 = (const float4*)W;

    int t = threadIdx.x;
    int brow = blockIdx.x * 128;
    int cg = t & 15, rg = t >> 4;

    float acc[8][8];
#pragma unroll
    for (int i = 0; i < 8; ++i)
#pragma unroll
        for (int j = 0; j < 8; ++j) acc[i][j] = 0.f;

    for (int kt = 0; kt < 2; ++kt) {
        // stage W rows kt*64..+63 (coalesced float4)
#pragma unroll
        for (int i = 0; i < 8; ++i) {
            int idx4 = t + i * 256;                 // 0..2047 float4s
            sW4[idx4] = W4[kt * 2048 + idx4];
        }
        // stage x^T: thread gathers 4 rows at one k, writes swizzled b128
        int kl = t & 63;
        int q = t >> 6;
#pragma unroll
        for (int i = 0; i < 8; ++i) {
            int rg4 = q + 4 * i;                    // row-group 0..31 (rows 4*rg4..+3)
            int r0 = brow + 4 * rg4;
            const float* xp = X + (size_t)r0 * 128 + kt * 64 + kl;
            float4 v;
            v.x = (r0 + 0 < N) ? xp[0]   : 0.f;
            v.y = (r0 + 1 < N) ? xp[128] : 0.f;
            v.z = (r0 + 2 < N) ? xp[256] : 0.f;
            v.w = (r0 + 3 < N) ? xp[384] : 0.f;
            sX4[(kl << 5) + (rg4 ^ (kl & 31))] = v;
        }
        __syncthreads();

#pragma unroll 2
        for (int kk = 0; kk < 64; ++kk) {
            float4 a0 = sX4[(kk << 5) + ((2 * rg)     ^ (kk & 31))];
            float4 a1 = sX4[(kk << 5) + ((2 * rg + 1) ^ (kk & 31))];
            float4 b0 = sW4[(kk << 5) + 2 * cg];
            float4 b1 = sW4[(kk << 5) + 2 * cg + 1];
            float a[8] = {a0.x, a0.y, a0.z, a0.w, a1.x, a1.y, a1.z, a1.w};
            float b[8] = {b0.x, b0.y, b0.z, b0.w, b1.x, b1.y, b1.z, b1.w};
#pragma unroll
            for (int i = 0; i < 8; ++i)
#pragma unroll
                for (int j = 0; j < 8; ++j)
                    acc[i][j] = fmaf(a[i], b[j], acc[i][j]);
        }
        __syncthreads();
    }

#pragma unroll
    for (int i = 0; i < 8; ++i) {
        int row = brow + 8 * rg + i;
        if (row < N) {
            float4* Hp = (float4*)(H + (size_t)row * 128 + 8 * cg);
            Hp[0] = make_float4(acc[i][0], acc[i][1], acc[i][2], acc[i][3]);
            Hp[1] = make_float4(acc[i][4], acc[i][5], acc[i][6], acc[i][7]);
        }
    }
}

// ------------- aggregate + bias + ReLU + LayerNorm (one wave per node) -------------
__global__ __launch_bounds__(256) void k_agg(const float* __restrict__ H,
                                             const int* __restrict__ rowptr,
                                             const int* __restrict__ col,
                                             const float* __restrict__ dinv,
                                             const float* __restrict__ bias,
                                             const float* __restrict__ gamma,
                                             const float* __restrict__ beta,
                                             float* __restrict__ out, int N) {
    int wave = threadIdx.x >> 6;
    int lane = threadIdx.x & 63;
    int node = blockIdx.x * 4 + wave;
    if (node >= N) return;

    const float2* H2 = (const float2*)H;
    float di = dinv[node];
    float2 hs = H2[(size_t)node * 64 + lane];
    float2 acc = make_float2(hs.x * di * di, hs.y * di * di);   // self-loop

    int beg = rowptr[node], end = rowptr[node + 1];
    for (int e = beg; e < end; ++e) {
        int s = col[e];
        float w = dinv[s] * di;
        float2 hv = H2[(size_t)s * 64 + lane];
        acc.x = fmaf(w, hv.x, acc.x);
        acc.y = fmaf(w, hv.y, acc.y);
    }

    float2 bb = ((const float2*)bias)[lane];
    float a0 = fmaxf(acc.x + bb.x, 0.f);
    float a1 = fmaxf(acc.y + bb.y, 0.f);

    float s1 = a0 + a1;
    float s2 = a0 * a0 + a1 * a1;
#pragma unroll
    for (int off = 32; off >= 1; off >>= 1) {
        s1 += __shfl_xor(s1, off);
        s2 += __shfl_xor(s2, off);
    }
    float mu = s1 * (1.f / 128.f);
    float var = s2 * (1.f / 128.f) - mu * mu;
    float rs = rsqrtf(var + LN_EPS);

    float2 g = ((const float2*)gamma)[lane];
    float2 be = ((const float2*)beta)[lane];
    float o0 = (a0 - mu) * rs * g.x + be.x;
    float o1 = (a1 - mu) * rs * g.y + be.y;
    ((float2*)out)[(size_t)node * 64 + lane] = make_float2(o0, o1);
}

// ---------------- launch ----------------
extern "C" void kernel_launch(void* const* d_in, const int* in_sizes, int n_in,
                              void* d_out, int out_size, void* d_ws, size_t ws_size,
                              hipStream_t stream) {
    const float* x  = (const float*)d_in[0];
    const int*   ei = (const int*)d_in[1];
    const float* W1 = (const float*)d_in[2];
    const float* b1 = (const float*)d_in[3];
    const float* W2 = (const float*)d_in[4];
    const float* b2 = (const float*)d_in[5];
    const float* g1 = (const float*)d_in[6];
    const float* be1 = (const float*)d_in[7];
    const float* g2 = (const float*)d_in[8];
    const float* be2 = (const float*)d_in[9];

    int N = in_sizes[0] / FDIM;
    int E = in_sizes[1] / 2;
    const int* srcp = ei;
    const int* dstp = ei + E;
    float* out = (float*)d_out;

    // workspace carve-up (256B aligned)
    char* w = (char*)d_ws;
    size_t off = 0;
    auto take = [&](size_t bytes) {
        void* p = w + off;
        off = (off + bytes + 255) & ~(size_t)255;
        return p;
    };
    float* hbuf  = (float*)take((size_t)N * FDIM * sizeof(float));
    int* cnt     = (int*)take((size_t)N * sizeof(int));
    int* rowptr  = (int*)take((size_t)(N + 1) * sizeof(int));
    int* pos     = (int*)take((size_t)E * sizeof(int));
    int* colb    = (int*)take((size_t)E * sizeof(int));
    float* dinv  = (float*)take((size_t)N * sizeof(float));
    int* partial = (int*)take(1024 * sizeof(int));
    (void)ws_size;

    int NB = (N + 1023) >> 10;

    // CSR build (shared by both layers)
    k_zero<<<(N + 255) / 256, 256, 0, stream>>>(cnt, N);
    k_count<<<(E + 255) / 256, 256, 0, stream>>>(dstp, cnt, pos, E);
    k_scan_block<<<NB, 1024, 0, stream>>>(cnt, rowptr, partial, N);
    k_scan_partial<<<1, 1024, 0, stream>>>(partial, NB);
    k_finalize<<<(N + 255) / 256, 256, 0, stream>>>(rowptr, partial, cnt, dinv, N, E);
    k_fill<<<(E + 255) / 256, 256, 0, stream>>>(srcp, dstp, rowptr, pos, colb, E);

    // layer 1
    k_gemm<<<(N + 127) / 128, 256, 0, stream>>>(x, W1, hbuf, N);
    k_agg<<<(N + 3) / 4, 256, 0, stream>>>(hbuf, rowptr, colb, dinv, b1, g1, be1, out, N);
    // layer 2 (reads d_out as input, overwrites it at the end)
    k_gemm<<<(N + 127) / 128, 256, 0, stream>>>(out, W2, hbuf, N);
    k_agg<<<(N + 3) / 4, 256, 0, stream>>>(hbuf, rowptr, colb, dinv, b2, g2, be2, out, N);
}

// Round 2
// 347.710 us; speedup vs baseline: 1.6727x; 1.6727x over previous
//
#include <hip/hip_runtime.h>

#define FDIM 128
#define LN_EPS 1e-5f

typedef short short8 __attribute__((ext_vector_type(8)));
typedef float f32x4 __attribute__((ext_vector_type(4)));

__device__ __forceinline__ ushort f2bf(float f) {
    uint u = __float_as_uint(f);
    u += 0x7fff + ((u >> 16) & 1);      // RNE (inputs are finite, no NaN care)
    return (ushort)(u >> 16);
}
__device__ __forceinline__ float bflo(uint u) { return __uint_as_float(u << 16); }
__device__ __forceinline__ float bfhi(uint u) { return __uint_as_float(u & 0xffff0000u); }

// ---------------- CSR build ----------------
__global__ void k_zero(int* __restrict__ cnt, int n) {
    int i = blockIdx.x * 256 + threadIdx.x;
    if (i < n) cnt[i] = 0;
}

__global__ void k_count(const int* __restrict__ dst, int* __restrict__ cnt,
                        int* __restrict__ pos, int E) {
    int e = blockIdx.x * 256 + threadIdx.x;
    if (e < E) pos[e] = atomicAdd(&cnt[dst[e]], 1);
}

__global__ __launch_bounds__(1024) void k_scan_block(const int* __restrict__ cnt,
                                                     int* __restrict__ rowptr,
                                                     int* __restrict__ partial, int N) {
    __shared__ int s[1024];
    int t = threadIdx.x;
    int i = blockIdx.x * 1024 + t;
    int v = (i < N) ? cnt[i] : 0;
    s[t] = v;
    __syncthreads();
    for (int off = 1; off < 1024; off <<= 1) {
        int u = (t >= off) ? s[t - off] : 0;
        __syncthreads();
        s[t] += u;
        __syncthreads();
    }
    if (i < N) rowptr[i] = s[t] - v;
    if (t == 1023) partial[blockIdx.x] = s[1023];
}

__global__ __launch_bounds__(1024) void k_scan_partial(int* __restrict__ partial, int NB) {
    __shared__ int s[1024];
    int t = threadIdx.x;
    int v = (t < NB) ? partial[t] : 0;
    s[t] = v;
    __syncthreads();
    for (int off = 1; off < 1024; off <<= 1) {
        int u = (t >= off) ? s[t - off] : 0;
        __syncthreads();
        s[t] += u;
        __syncthreads();
    }
    if (t < NB) partial[t] = s[t] - v;
}

__global__ void k_finalize(int* __restrict__ rowptr, const int* __restrict__ partial,
                           const int* __restrict__ cnt, float* __restrict__ dinv,
                           int N, int E) {
    int i = blockIdx.x * 256 + threadIdx.x;
    if (i < N) {
        rowptr[i] += partial[i >> 10];
        dinv[i] = rsqrtf((float)cnt[i] + 1.0f);
    }
    if (i == 0) rowptr[N] = E;
}

__global__ void k_fill(const int* __restrict__ src, const int* __restrict__ dst,
                       const int* __restrict__ rowptr, const int* __restrict__ pos,
                       int* __restrict__ col, int E) {
    int e = blockIdx.x * 256 + threadIdx.x;
    if (e < E) col[rowptr[dst[e]] + pos[e]] = src[e];
}

// ---------------- fp32 -> bf16 convert (x) ----------------
__global__ void k_cvt(const float* __restrict__ X, ushort* __restrict__ Xb, int n4) {
    int i = blockIdx.x * 256 + threadIdx.x;
    if (i < n4) {
        float4 v = ((const float4*)X)[i];
        ushort4 o;
        o.x = f2bf(v.x); o.y = f2bf(v.y); o.z = f2bf(v.z); o.w = f2bf(v.w);
        ((ushort4*)Xb)[i] = o;
    }
}

// ---------------- W[128,128] fp32 -> W^T bf16 ----------------
__global__ void k_wt(const float* __restrict__ W, ushort* __restrict__ WT) {
    int n = blockIdx.x, k = threadIdx.x;
    WT[n * 128 + k] = f2bf(W[k * 128 + n]);
}

// ---------------- MFMA GEMM: H_bf16[N,128] = Xb[N,128] @ WT^T ----------------
// 256 thr = 4 waves, 16 rows/wave. A frags direct from global (per-lane 16B,
// 4 kc covers the row). B frags direct from global WT (32KB, L1/L2-resident).
// mfma_f32_16x16x32_bf16: A row=lane&15, k=(lane>>4)*8+j ; B col=lane&15 same k;
// D col=lane&15, row=(lane>>4)*4+reg (m89).
__global__ __launch_bounds__(256) void k_gemm(const ushort* __restrict__ Xb,
                                              const ushort* __restrict__ WT,
                                              ushort* __restrict__ H, int N) {
    int w = threadIdx.x >> 6, lane = threadIdx.x & 63;
    int cl = lane & 15, kq = lane >> 4;
    int r = blockIdx.x * 64 + w * 16 + cl;
    int rc = min(r, N - 1);
    const short8* X8 = (const short8*)Xb;
    const short8* W8 = (const short8*)WT;

    short8 a0 = X8[rc * 16 + 0 * 4 + kq];
    short8 a1 = X8[rc * 16 + 1 * 4 + kq];
    short8 a2 = X8[rc * 16 + 2 * 4 + kq];
    short8 a3 = X8[rc * 16 + 3 * 4 + kq];

    int rowbase = blockIdx.x * 64 + w * 16 + kq * 4;
#pragma unroll
    for (int nt = 0; nt < 8; ++nt) {
        int col = nt * 16 + cl;
        f32x4 acc = {0.f, 0.f, 0.f, 0.f};
        acc = __builtin_amdgcn_mfma_f32_16x16x32_bf16(a0, W8[col * 16 + 0 * 4 + kq], acc, 0, 0, 0);
        acc = __builtin_amdgcn_mfma_f32_16x16x32_bf16(a1, W8[col * 16 + 1 * 4 + kq], acc, 0, 0, 0);
        acc = __builtin_amdgcn_mfma_f32_16x16x32_bf16(a2, W8[col * 16 + 2 * 4 + kq], acc, 0, 0, 0);
        acc = __builtin_amdgcn_mfma_f32_16x16x32_bf16(a3, W8[col * 16 + 3 * 4 + kq], acc, 0, 0, 0);
#pragma unroll
        for (int j = 0; j < 4; ++j) {
            int row = rowbase + j;
            if (row < N) H[(size_t)row * 128 + col] = f2bf(acc[j]);
        }
    }
}

// ------------- aggregate(bf16 h) + bias + ReLU + LN; out fp32 or bf16 -------------
__global__ __launch_bounds__(256) void k_agg(const uint* __restrict__ H,   // bf16x2
                                             const int* __restrict__ rowptr,
                                             const int* __restrict__ col,
                                             const float* __restrict__ dinv,
                                             const float* __restrict__ bias,
                                             const float* __restrict__ gamma,
                                             const float* __restrict__ beta,
                                             float* __restrict__ outf,
                                             uint* __restrict__ outb,
                                             int N) {
    int wave = threadIdx.x >> 6;
    int lane = threadIdx.x & 63;
    int node = blockIdx.x * 4 + wave;
    if (node >= N) return;

    float di = dinv[node];
    uint hs = H[(size_t)node * 64 + lane];
    float ax = di * bflo(hs);          // inner = di*h_self + sum dinv[s]*h[s]
    float ay = di * bfhi(hs);

    int e = rowptr[node], end = rowptr[node + 1];
    for (; e + 4 <= end; e += 4) {
        int s0 = col[e + 0], s1 = col[e + 1], s2 = col[e + 2], s3 = col[e + 3];
        float w0 = dinv[s0], w1 = dinv[s1], w2 = dinv[s2], w3 = dinv[s3];
        uint u0 = H[(size_t)s0 * 64 + lane];
        uint u1 = H[(size_t)s1 * 64 + lane];
        uint u2 = H[(size_t)s2 * 64 + lane];
        uint u3 = H[(size_t)s3 * 64 + lane];
        ax = fmaf(w0, bflo(u0), ax); ay = fmaf(w0, bfhi(u0), ay);
        ax = fmaf(w1, bflo(u1), ax); ay = fmaf(w1, bfhi(u1), ay);
        ax = fmaf(w2, bflo(u2), ax); ay = fmaf(w2, bfhi(u2), ay);
        ax = fmaf(w3, bflo(u3), ax); ay = fmaf(w3, bfhi(u3), ay);
    }
    for (; e < end; ++e) {
        int s = col[e];
        float ww = dinv[s];
        uint u = H[(size_t)s * 64 + lane];
        ax = fmaf(ww, bflo(u), ax); ay = fmaf(ww, bfhi(u), ay);
    }

    float2 bb = ((const float2*)bias)[lane];
    float a0 = fmaxf(fmaf(ax, di, bb.x), 0.f);
    float a1 = fmaxf(fmaf(ay, di, bb.y), 0.f);

    float s1 = a0 + a1;
    float s2 = a0 * a0 + a1 * a1;
#pragma unroll
    for (int off = 32; off >= 1; off >>= 1) {
        s1 += __shfl_xor(s1, off);
        s2 += __shfl_xor(s2, off);
    }
    float mu = s1 * (1.f / 128.f);
    float var = s2 * (1.f / 128.f) - mu * mu;
    float rs = rsqrtf(var + LN_EPS);

    float2 g = ((const float2*)gamma)[lane];
    float2 be = ((const float2*)beta)[lane];
    float o0 = (a0 - mu) * rs * g.x + be.x;
    float o1 = (a1 - mu) * rs * g.y + be.y;
    if (outf) {
        ((float2*)outf)[(size_t)node * 64 + lane] = make_float2(o0, o1);
    } else {
        outb[(size_t)node * 64 + lane] = (uint)f2bf(o0) | ((uint)f2bf(o1) << 16);
    }
}

// ---------------- launch ----------------
extern "C" void kernel_launch(void* const* d_in, const int* in_sizes, int n_in,
                              void* d_out, int out_size, void* d_ws, size_t ws_size,
                              hipStream_t stream) {
    const float* x  = (const float*)d_in[0];
    const int*   ei = (const int*)d_in[1];
    const float* W1 = (const float*)d_in[2];
    const float* b1 = (const float*)d_in[3];
    const float* W2 = (const float*)d_in[4];
    const float* b2 = (const float*)d_in[5];
    const float* g1 = (const float*)d_in[6];
    const float* be1 = (const float*)d_in[7];
    const float* g2 = (const float*)d_in[8];
    const float* be2 = (const float*)d_in[9];

    int N = in_sizes[0] / FDIM;
    int E = in_sizes[1] / 2;
    const int* srcp = ei;
    const int* dstp = ei + E;
    float* out = (float*)d_out;

    char* w = (char*)d_ws;
    size_t off = 0;
    auto take = [&](size_t bytes) {
        void* p = w + off;
        off = (off + bytes + 255) & ~(size_t)255;
        return p;
    };
    ushort* xb   = (ushort*)take((size_t)N * FDIM * sizeof(ushort));   // x in bf16
    ushort* hb   = (ushort*)take((size_t)N * FDIM * sizeof(ushort));   // gemm out bf16
    ushort* WT1  = (ushort*)take(128 * 128 * sizeof(ushort));
    ushort* WT2  = (ushort*)take(128 * 128 * sizeof(ushort));
    int* cnt     = (int*)take((size_t)N * sizeof(int));
    int* rowptr  = (int*)take((size_t)(N + 1) * sizeof(int));
    int* pos     = (int*)take((size_t)E * sizeof(int));
    int* colb    = (int*)take((size_t)E * sizeof(int));
    float* dinv  = (float*)take((size_t)N * sizeof(float));
    int* partial = (int*)take(1024 * sizeof(int));
    (void)ws_size;

    int NB = (N + 1023) >> 10;

    // CSR build (shared by both layers)
    k_zero<<<(N + 255) / 256, 256, 0, stream>>>(cnt, N);
    k_count<<<(E + 255) / 256, 256, 0, stream>>>(dstp, cnt, pos, E);
    k_scan_block<<<NB, 1024, 0, stream>>>(cnt, rowptr, partial, N);
    k_scan_partial<<<1, 1024, 0, stream>>>(partial, NB);
    k_finalize<<<(N + 255) / 256, 256, 0, stream>>>(rowptr, partial, cnt, dinv, N, E);
    k_fill<<<(E + 255) / 256, 256, 0, stream>>>(srcp, dstp, rowptr, pos, colb, E);

    // prep: x -> bf16, W -> W^T bf16
    k_cvt<<<((N * FDIM / 4) + 255) / 256, 256, 0, stream>>>(x, xb, N * FDIM / 4);
    k_wt<<<128, 128, 0, stream>>>(W1, WT1);
    k_wt<<<128, 128, 0, stream>>>(W2, WT2);

    // layer 1: gemm -> agg (bf16 out into front half of d_out)
    k_gemm<<<(N + 63) / 64, 256, 0, stream>>>(xb, WT1, hb, N);
    k_agg<<<(N + 3) / 4, 256, 0, stream>>>((const uint*)hb, rowptr, colb, dinv,
                                           b1, g1, be1, nullptr, (uint*)d_out, N);
    // layer 2: gemm reads bf16 from d_out, agg writes final fp32 d_out
    k_gemm<<<(N + 63) / 64, 256, 0, stream>>>((const ushort*)d_out, WT2, hb, N);
    k_agg<<<(N + 3) / 4, 256, 0, stream>>>((const uint*)hb, rowptr, colb, dinv,
                                           b2, g2, be2, out, nullptr, N);
}

// Round 3
// 347.116 us; speedup vs baseline: 1.6756x; 1.0017x over previous
//
#include <hip/hip_runtime.h>

#define FDIM 128
#define LN_EPS 1e-5f

typedef short short8 __attribute__((ext_vector_type(8)));
typedef float f32x4 __attribute__((ext_vector_type(4)));

__device__ __forceinline__ ushort f2bf(float f) {
    uint u = __float_as_uint(f);
    u += 0x7fff + ((u >> 16) & 1);      // RNE
    return (ushort)(u >> 16);
}
__device__ __forceinline__ float bflo(uint u) { return __uint_as_float(u << 16); }
__device__ __forceinline__ float bfhi(uint u) { return __uint_as_float(u & 0xffff0000u); }

// ---------------- CSR build ----------------
__global__ void k_zero(int* __restrict__ cnt, int n) {
    int i = blockIdx.x * 256 + threadIdx.x;
    if (i < n) cnt[i] = 0;
}

__global__ void k_count(const int* __restrict__ dst, int* __restrict__ cnt,
                        int* __restrict__ pos, int E) {
    int e = blockIdx.x * 256 + threadIdx.x;
    if (e < E) pos[e] = atomicAdd(&cnt[dst[e]], 1);
}

__global__ __launch_bounds__(1024) void k_scan_block(const int* __restrict__ cnt,
                                                     int* __restrict__ rowptr,
                                                     int* __restrict__ partial, int N) {
    __shared__ int s[1024];
    int t = threadIdx.x;
    int i = blockIdx.x * 1024 + t;
    int v = (i < N) ? cnt[i] : 0;
    s[t] = v;
    __syncthreads();
    for (int off = 1; off < 1024; off <<= 1) {
        int u = (t >= off) ? s[t - off] : 0;
        __syncthreads();
        s[t] += u;
        __syncthreads();
    }
    if (i < N) rowptr[i] = s[t] - v;
    if (t == 1023) partial[blockIdx.x] = s[1023];
}

__global__ __launch_bounds__(1024) void k_scan_partial(int* __restrict__ partial, int NB) {
    __shared__ int s[1024];
    int t = threadIdx.x;
    int v = (t < NB) ? partial[t] : 0;
    s[t] = v;
    __syncthreads();
    for (int off = 1; off < 1024; off <<= 1) {
        int u = (t >= off) ? s[t - off] : 0;
        __syncthreads();
        s[t] += u;
        __syncthreads();
    }
    if (t < NB) partial[t] = s[t] - v;
}

__global__ void k_finalize(int* __restrict__ rowptr, const int* __restrict__ partial,
                           const int* __restrict__ cnt, float* __restrict__ dinv,
                           int N, int E) {
    int i = blockIdx.x * 256 + threadIdx.x;
    if (i < N) {
        rowptr[i] += partial[i >> 10];
        dinv[i] = rsqrtf((float)cnt[i] + 1.0f);
    }
    if (i == 0) rowptr[N] = E;
}

__global__ void k_fill(const int* __restrict__ src, const int* __restrict__ dst,
                       const int* __restrict__ rowptr, const int* __restrict__ pos,
                       int* __restrict__ col, int E) {
    int e = blockIdx.x * 256 + threadIdx.x;
    if (e < E) col[rowptr[dst[e]] + pos[e]] = src[e];
}

// ---------------- W[128,128] fp32 -> W^T bf16 ----------------
__global__ void k_wt(const float* __restrict__ W, ushort* __restrict__ WT) {
    int n = blockIdx.x, k = threadIdx.x;
    WT[n * 128 + k] = f2bf(W[k * 128 + n]);
}

// ---------------- MFMA GEMM: H_bf16[N,128] = X[N,128] @ WT^T ----------------
// Swapped operands: mfma(a=W-col frag, b=X-row frag) -> D holds, per lane,
// output row r=lane&15 and 4 CONSECUTIVE cols c=(lane>>4)*4+reg  =>  8B stores.
template <bool F32IN>
__global__ __launch_bounds__(256) void k_gemm(const void* __restrict__ Xin,
                                              const ushort* __restrict__ WT,
                                              ushort* __restrict__ H, int N) {
    int w = threadIdx.x >> 6, lane = threadIdx.x & 63;
    int cl = lane & 15, kq = lane >> 4;
    int r = blockIdx.x * 64 + w * 16 + cl;
    int rc = min(r, N - 1);
    const short8* W8 = (const short8*)WT;

    short8 b0, b1, b2, b3;   // X row rc, k-chunks kt*32 + kq*8 .. +7
    if constexpr (F32IN) {
        const float4* X4 = (const float4*)((const float*)Xin + (size_t)rc * 128);
#pragma unroll
        for (int kt = 0; kt < 4; ++kt) {
            float4 v0 = X4[kt * 8 + kq * 2];
            float4 v1 = X4[kt * 8 + kq * 2 + 1];
            short8 o;
            o[0] = (short)f2bf(v0.x); o[1] = (short)f2bf(v0.y);
            o[2] = (short)f2bf(v0.z); o[3] = (short)f2bf(v0.w);
            o[4] = (short)f2bf(v1.x); o[5] = (short)f2bf(v1.y);
            o[6] = (short)f2bf(v1.z); o[7] = (short)f2bf(v1.w);
            if (kt == 0) b0 = o; else if (kt == 1) b1 = o; else if (kt == 2) b2 = o; else b3 = o;
        }
    } else {
        const short8* X8 = (const short8*)Xin;
        b0 = X8[(size_t)rc * 16 + 0 * 4 + kq];
        b1 = X8[(size_t)rc * 16 + 1 * 4 + kq];
        b2 = X8[(size_t)rc * 16 + 2 * 4 + kq];
        b3 = X8[(size_t)rc * 16 + 3 * 4 + kq];
    }

    bool ok = r < N;
#pragma unroll
    for (int nt = 0; nt < 8; ++nt) {
        int c = nt * 16 + cl;                      // WT row = W col
        f32x4 acc = {0.f, 0.f, 0.f, 0.f};
        acc = __builtin_amdgcn_mfma_f32_16x16x32_bf16(W8[c * 16 + 0 * 4 + kq], b0, acc, 0, 0, 0);
        acc = __builtin_amdgcn_mfma_f32_16x16x32_bf16(W8[c * 16 + 1 * 4 + kq], b1, acc, 0, 0, 0);
        acc = __builtin_amdgcn_mfma_f32_16x16x32_bf16(W8[c * 16 + 2 * 4 + kq], b2, acc, 0, 0, 0);
        acc = __builtin_amdgcn_mfma_f32_16x16x32_bf16(W8[c * 16 + 3 * 4 + kq], b3, acc, 0, 0, 0);
        if (ok) {
            ushort4 o;
            o.x = f2bf(acc[0]); o.y = f2bf(acc[1]);
            o.z = f2bf(acc[2]); o.w = f2bf(acc[3]);
            *(ushort4*)(H + (size_t)r * 128 + nt * 16 + kq * 4) = o;
        }
    }
}

// ------- aggregate(bf16 h) + bias + ReLU + LN; 2 nodes/wave, uint2 gathers -------
__global__ __launch_bounds__(256) void k_agg(const uint2* __restrict__ H2,
                                             const int* __restrict__ rowptr,
                                             const int* __restrict__ col,
                                             const float* __restrict__ dinv,
                                             const float* __restrict__ bias,
                                             const float* __restrict__ gamma,
                                             const float* __restrict__ beta,
                                             float* __restrict__ outf,
                                             uint2* __restrict__ outb,
                                             int N) {
    int wave = threadIdx.x >> 6;
    int lane = threadIdx.x & 63;
    int half = lane >> 5;
    int l = lane & 31;                     // covers features 4l..4l+3
    int node = blockIdx.x * 8 + wave * 2 + half;
    bool valid = node < N;
    int nodec = valid ? node : N - 1;

    float di = dinv[nodec];
    uint2 hs = H2[(size_t)nodec * 32 + l];
    float ax = di * bflo(hs.x), ay = di * bfhi(hs.x);
    float az = di * bflo(hs.y), aw = di * bfhi(hs.y);

    int beg = rowptr[nodec];
    int deg = rowptr[nodec + 1] - beg;
    int mx = max(deg, __shfl_xor(deg, 32));      // pair max
    int mx4 = (mx + 3) & ~3;

#define EDGE(ii)                                                            \
    {                                                                       \
        bool act = (ii) < deg;                                              \
        int s = act ? col[beg + (ii)] : 0;                                  \
        float ww = act ? dinv[s] : 0.f;                                     \
        uint2 u = H2[(size_t)s * 32 + l];                                   \
        ax = fmaf(ww, bflo(u.x), ax); ay = fmaf(ww, bfhi(u.x), ay);         \
        az = fmaf(ww, bflo(u.y), az); aw = fmaf(ww, bfhi(u.y), aw);         \
    }

    for (int i = 0; i < mx4; i += 4) {
        EDGE(i + 0)
        EDGE(i + 1)
        EDGE(i + 2)
        EDGE(i + 3)
    }
#undef EDGE

    float4 bb = ((const float4*)bias)[l];
    float a0 = fmaxf(fmaf(ax, di, bb.x), 0.f);
    float a1 = fmaxf(fmaf(ay, di, bb.y), 0.f);
    float a2 = fmaxf(fmaf(az, di, bb.z), 0.f);
    float a3 = fmaxf(fmaf(aw, di, bb.w), 0.f);

    float s1 = a0 + a1 + a2 + a3;
    float s2 = a0 * a0 + a1 * a1 + a2 * a2 + a3 * a3;
#pragma unroll
    for (int off = 16; off >= 1; off >>= 1) {     // width-32 butterfly
        s1 += __shfl_xor(s1, off);
        s2 += __shfl_xor(s2, off);
    }
    float mu = s1 * (1.f / 128.f);
    float var = s2 * (1.f / 128.f) - mu * mu;
    float rs = rsqrtf(var + LN_EPS);

    float4 g = ((const float4*)gamma)[l];
    float4 be = ((const float4*)beta)[l];
    float o0 = (a0 - mu) * rs * g.x + be.x;
    float o1 = (a1 - mu) * rs * g.y + be.y;
    float o2 = (a2 - mu) * rs * g.z + be.z;
    float o3 = (a3 - mu) * rs * g.w + be.w;

    if (!valid) return;
    if (outf) {
        ((float4*)outf)[(size_t)node * 32 + l] = make_float4(o0, o1, o2, o3);
    } else {
        uint2 o;
        o.x = (uint)f2bf(o0) | ((uint)f2bf(o1) << 16);
        o.y = (uint)f2bf(o2) | ((uint)f2bf(o3) << 16);
        outb[(size_t)node * 32 + l] = o;
    }
}

// ---------------- launch ----------------
extern "C" void kernel_launch(void* const* d_in, const int* in_sizes, int n_in,
                              void* d_out, int out_size, void* d_ws, size_t ws_size,
                              hipStream_t stream) {
    const float* x  = (const float*)d_in[0];
    const int*   ei = (const int*)d_in[1];
    const float* W1 = (const float*)d_in[2];
    const float* b1 = (const float*)d_in[3];
    const float* W2 = (const float*)d_in[4];
    const float* b2 = (const float*)d_in[5];
    const float* g1 = (const float*)d_in[6];
    const float* be1 = (const float*)d_in[7];
    const float* g2 = (const float*)d_in[8];
    const float* be2 = (const float*)d_in[9];

    int N = in_sizes[0] / FDIM;
    int E = in_sizes[1] / 2;
    const int* srcp = ei;
    const int* dstp = ei + E;
    float* out = (float*)d_out;

    char* w = (char*)d_ws;
    size_t off = 0;
    auto take = [&](size_t bytes) {
        void* p = w + off;
        off = (off + bytes + 255) & ~(size_t)255;
        return p;
    };
    ushort* hb   = (ushort*)take((size_t)N * FDIM * sizeof(ushort));   // gemm out bf16
    ushort* WT1  = (ushort*)take(128 * 128 * sizeof(ushort));
    ushort* WT2  = (ushort*)take(128 * 128 * sizeof(ushort));
    int* cnt     = (int*)take((size_t)N * sizeof(int));
    int* rowptr  = (int*)take((size_t)(N + 1) * sizeof(int));
    int* pos     = (int*)take((size_t)E * sizeof(int));
    int* colb    = (int*)take((size_t)E * sizeof(int));
    float* dinv  = (float*)take((size_t)N * sizeof(float));
    int* partial = (int*)take(1024 * sizeof(int));
    (void)ws_size;

    int NB = (N + 1023) >> 10;

    // CSR build (shared by both layers)
    k_zero<<<(N + 255) / 256, 256, 0, stream>>>(cnt, N);
    k_count<<<(E + 255) / 256, 256, 0, stream>>>(dstp, cnt, pos, E);
    k_scan_block<<<NB, 1024, 0, stream>>>(cnt, rowptr, partial, N);
    k_scan_partial<<<1, 1024, 0, stream>>>(partial, NB);
    k_finalize<<<(N + 255) / 256, 256, 0, stream>>>(rowptr, partial, cnt, dinv, N, E);
    k_fill<<<(E + 255) / 256, 256, 0, stream>>>(srcp, dstp, rowptr, pos, colb, E);

    // weights -> W^T bf16
    k_wt<<<128, 128, 0, stream>>>(W1, WT1);
    k_wt<<<128, 128, 0, stream>>>(W2, WT2);

    // layer 1: gemm (fp32 in, convert fused) -> agg (bf16 out into d_out front)
    k_gemm<true><<<(N + 63) / 64, 256, 0, stream>>>(x, WT1, hb, N);
    k_agg<<<(N + 7) / 8, 256, 0, stream>>>((const uint2*)hb, rowptr, colb, dinv,
                                           b1, g1, be1, nullptr, (uint2*)d_out, N);
    // layer 2: gemm reads bf16 from d_out, agg writes final fp32 d_out
    k_gemm<false><<<(N + 63) / 64, 256, 0, stream>>>(d_out, WT2, hb, N);
    k_agg<<<(N + 7) / 8, 256, 0, stream>>>((const uint2*)hb, rowptr, colb, dinv,
                                           b2, g2, be2, out, nullptr, N);
}